// Round 15
// baseline (730.212 us; speedup 1.0000x reference)
//
#include <hip/hip_runtime.h>

// ---------------------------------------------------------------------------
// Seq2Seq: encoder LSTM (128 steps) -> decoder LSTM (127 steps) -> FC to vocab
// B=32, S=T=128, V=32000, E=H=256
//
// R15 = R14 with fc at 4 blocks/CU: As dropped (A fragments read straight
// from L2-resident hs), LDS = Bs[128][136] only (34.8 KB); epilogue done as
// two 64-row half-tiles through a Ct[64][132] overlay -> keeps the proven
// full-512B-segment nt stores. 16 waves/CU hide the store drain.
// lstm (R9 structure) untouched.
// ---------------------------------------------------------------------------

typedef __attribute__((ext_vector_type(8))) short bf16x8;
typedef __attribute__((ext_vector_type(4))) float f32x4;
typedef __attribute__((ext_vector_type(8))) unsigned short u16x8;
typedef __attribute__((ext_vector_type(4))) unsigned int u32x4;
typedef __attribute__((ext_vector_type(8))) _Float16 f16x8;
typedef __attribute__((ext_vector_type(2))) _Float16 h2;

// workspace byte offsets (all 256-aligned)
#define WS_XG_E   0u          // 128*32*1024 f32 = 16,777,216 B
#define WS_XG_D   16777216u   // 127*32*1024 f32 = 16,646,144 B
#define WS_FCW    33423360u   // 32000*256 bf16  = 16,384,000 B
#define WS_HS     49807360u   // 4096*256 bf16   =  2,097,152 B (padded [b*128+t])
#define WS_WTE    51904512u   // 1024*256 f16    =    524,288 B
#define WS_WTD    52428800u   // 1024*256 f16    =    524,288 B

#define KC_REG 48   // weight chunks in registers (gates i,f,g)
#define KC_LDS 16   // weight chunks in LDS (gate o) = 128 KB

__device__ __forceinline__ unsigned short f2bf(float f) {
  unsigned u = __float_as_uint(f);
  u += 0x7FFFu + ((u >> 16) & 1u);   // round-to-nearest-even
  return (unsigned short)(u >> 16);
}

__device__ __forceinline__ float sigf(float x) {
  float e = __expf(-x);
  return __builtin_amdgcn_rcpf(1.f + e);
}
__device__ __forceinline__ float tanh_fast(float x) {
  float e = __expf(-2.f * x);
  return fmaf(2.f, __builtin_amdgcn_rcpf(1.f + e), -1.f);  // (1-e)/(1+e)
}

#if __has_builtin(__builtin_amdgcn_fdot2)
#define FDOT2(a, w, h) a = __builtin_amdgcn_fdot2(w, h, a, false)
#else
#define FDOT2(a, w, h) a = fmaf((float)w[0], (float)h[0], fmaf((float)w[1], (float)h[1], a))
#endif

// 8 f16 weights vs 8 f16 h values -> two accumulator chains
__device__ __forceinline__ void dot8(const u16x8 w, const u32x4 hbits,
                                     float& a0, float& a1) {
  f16x8 wv = __builtin_bit_cast(f16x8, w);
  f16x8 hv = __builtin_bit_cast(f16x8, hbits);
  h2 w0 = {wv[0], wv[1]}, w1 = {wv[2], wv[3]};
  h2 w2 = {wv[4], wv[5]}, w3 = {wv[6], wv[7]};
  h2 h0 = {hv[0], hv[1]}, h1 = {hv[2], hv[3]};
  h2 hc = {hv[4], hv[5]}, h3 = {hv[6], hv[7]};
  FDOT2(a0, w0, h0);
  FDOT2(a1, w1, h1);
  FDOT2(a0, w2, hc);
  FDOT2(a1, w3, h3);
}

// ---------------------------------------------------------------------------
__global__ __launch_bounds__(256) void zero_col0(float* __restrict__ out) {
  int i = blockIdx.x * 256 + threadIdx.x;        // 256,000 float4s total
  int b = i / 8000;
  int r = i - b * 8000;
  f32x4 z = {0.f, 0.f, 0.f, 0.f};
  __builtin_nontemporal_store(z, (f32x4*)out + b * 1024000 + r);
}

__global__ __launch_bounds__(256) void cvt_bf16(const float* __restrict__ in,
                                                unsigned short* __restrict__ o,
                                                int n4) {
  int i = blockIdx.x * 256 + threadIdx.x;
  if (i < n4) {
    float4 v = ((const float4*)in)[i];
    ushort4 u;
    u.x = f2bf(v.x); u.y = f2bf(v.y); u.z = f2bf(v.z); u.w = f2bf(v.w);
    *(ushort4*)(o + i * 4) = u;
  }
}

// Whh[1024 r][256 k] -> f16 T[chunk j][512 tid][8 e], j = gate*16 + kk.
__global__ __launch_bounds__(256) void prep_whalf(const float* __restrict__ We,
                                                  const float* __restrict__ Wd,
                                                  unsigned short* __restrict__ Te,
                                                  unsigned short* __restrict__ Td) {
  int d = blockIdx.x * 256 + threadIdx.x;       // 0..262143
  const float* W = blockIdx.y ? Wd : We;
  unsigned short* T = blockIdx.y ? Td : Te;
  int e = d & 7;
  int tmp = d >> 3;
  int tidb = tmp & 511;
  int j = tmp >> 9;                 // 0..63
  int gg = j >> 4, kk = j & 15;
  int wv = tidb >> 6, ln = tidb & 63;
  int qq = ln >> 5, dm = wv * 32 + (ln & 31);
  _Float16 v = (_Float16)W[(gg * 256 + dm) * 256 + qq * 128 + kk * 8 + e];
  T[d] = __builtin_bit_cast(unsigned short, v);
}

// ---------------------------------------------------------------------------
// xg[row][n] = emb[token(row)] @ Wih^T + bias ; row = t*32 + b
__global__ __launch_bounds__(256) void xg_gemm(
    const int* __restrict__ tok, const float* __restrict__ emb,
    const float* __restrict__ Wih, const float* __restrict__ bias,
    float* __restrict__ xg, const int Mrows) {
  __shared__ unsigned short As[128][264];  // +8 bf16 pad -> 2-way (free)
  __shared__ unsigned short Bs[128][264];
  const int tid = threadIdx.x;
  const int nb = blockIdx.x, rb = blockIdx.y;
  {
    int lr = tid >> 1, half = tid & 1;
    int cb = half * 128;
    int row = rb * 128 + lr;
    int rowc = row < Mrows ? row : (Mrows - 1);
    int tt = rowc >> 5, bb = rowc & 31;
    int tk = tok[bb * 128 + tt];
    const float4* sa = (const float4*)(emb + tk * 256 + cb);
    const float4* sb = (const float4*)(Wih + (nb * 128 + lr) * 256 + cb);
#pragma unroll
    for (int i = 0; i < 32; ++i) {
      float4 v = sa[i];
      ushort4 u;
      u.x = f2bf(v.x); u.y = f2bf(v.y); u.z = f2bf(v.z); u.w = f2bf(v.w);
      *(ushort4*)&As[lr][cb + i * 4] = u;
      float4 v2 = sb[i];
      ushort4 u2;
      u2.x = f2bf(v2.x); u2.y = f2bf(v2.y); u2.z = f2bf(v2.z); u2.w = f2bf(v2.w);
      *(ushort4*)&Bs[lr][cb + i * 4] = u2;
    }
  }
  __syncthreads();
  const int lane = tid & 63, w = tid >> 6;
  const int wr = w >> 1, wc = w & 1;
  const int fr = lane & 15, kg = lane >> 4;
  f32x4 acc[4][4];
  const f32x4 zero = {0.f, 0.f, 0.f, 0.f};
#pragma unroll
  for (int mi = 0; mi < 4; ++mi)
#pragma unroll
    for (int ni = 0; ni < 4; ++ni) acc[mi][ni] = zero;
#pragma unroll
  for (int ks = 0; ks < 8; ++ks) {
    const int kb = ks * 32 + kg * 8;
    bf16x8 a[4], b[4];
#pragma unroll
    for (int mi = 0; mi < 4; ++mi)
      a[mi] = *(const bf16x8*)&As[wr * 64 + mi * 16 + fr][kb];
#pragma unroll
    for (int ni = 0; ni < 4; ++ni)
      b[ni] = *(const bf16x8*)&Bs[wc * 64 + ni * 16 + fr][kb];
#pragma unroll
    for (int mi = 0; mi < 4; ++mi)
#pragma unroll
      for (int ni = 0; ni < 4; ++ni)
        acc[mi][ni] = __builtin_amdgcn_mfma_f32_16x16x32_bf16(a[mi], b[ni], acc[mi][ni], 0, 0, 0);
  }
#pragma unroll
  for (int ni = 0; ni < 4; ++ni) {
    const int colg = nb * 128 + wc * 64 + ni * 16 + fr;
    const float bv = bias[colg];
#pragma unroll
    for (int mi = 0; mi < 4; ++mi) {
#pragma unroll
      for (int r = 0; r < 4; ++r) {
        int rowg = rb * 128 + wr * 64 + mi * 16 + kg * 4 + r;
        if (rowg < Mrows) xg[rowg * 1024 + colg] = acc[mi][ni][r] + bv;
      }
    }
  }
}

// ---------------------------------------------------------------------------
// Per-batch LSTM chain (R9). Block b (32 blocks x 512 thr, 1 block/CU).
__global__ __launch_bounds__(512, 2) void lstm_batch(
    const unsigned short* __restrict__ WTe, const unsigned short* __restrict__ WTd,
    const float* __restrict__ xgE, const float* __restrict__ xgD,
    unsigned short* __restrict__ hs) {
  __shared__ __align__(16) unsigned short hh[2][256];        // h as f16, dbuf
  __shared__ __align__(16) unsigned short wl[KC_LDS * 4096]; // 128 KB (o gate)
  const int tid = threadIdx.x;   // 0..511
  const int b = blockIdx.x;
  const int l = tid & 63, w = tid >> 6;
  const int q = l >> 5;                 // k-half
  const int dim = w * 32 + (l & 31);
  float c = 0.f;
  int cur = 0;
  if (tid < 256) hh[0][tid] = 0;        // h0 = 0 (f16 zero bits)

  for (int phase = 0; phase < 2; ++phase) {
    const unsigned short* WT = phase ? WTd : WTe;
    const float* xg = phase ? xgD : xgE;
    const int steps = phase ? 127 : 128;
    const u16x8* wsrc = (const u16x8*)WT + tid;
    u16x8 wr[KC_REG];
#pragma unroll
    for (int j = 0; j < KC_REG; ++j) wr[j] = wsrc[j * 512];
    __syncthreads();   // prev phase's wl reads complete before overwrite
    {
      u16x8* ld = (u16x8*)wl + tid;
#pragma unroll
      for (int j = 0; j < KC_LDS; ++j) ld[j * 512] = wsrc[(KC_REG + j) * 512];
    }
    __syncthreads();   // wl + hh visible

    for (int t = 0; t < steps; ++t) {
      const float* xr = xg + (t * 32 + b) * 1024 + dim;
      float x0 = xr[0], x1 = xr[256], x2 = xr[512], x3 = xr[768];
      const u32x4* hq = (const u32x4*)&hh[cur][q * 128];
      const u16x8* wlp = (const u16x8*)wl + tid;
      float ai0 = 0.f, ai1 = 0.f, af0 = 0.f, af1 = 0.f;
      float ag0 = 0.f, ag1 = 0.f, ao0 = 0.f, ao1 = 0.f;
#pragma unroll
      for (int kk = 0; kk < 16; ++kk) {
        u32x4 hv = hq[kk];
        dot8(wr[kk],        hv, ai0, ai1);
        dot8(wr[16 + kk],   hv, af0, af1);
        dot8(wr[32 + kk],   hv, ag0, ag1);
        dot8(wlp[kk * 512], hv, ao0, ao1);
      }
      float gi = ai0 + ai1, gf = af0 + af1;
      float gg = ag0 + ag1, go = ao0 + ao1;
      gi += __shfl_xor(gi, 32, 64);     // combine k-halves (butterfly)
      gf += __shfl_xor(gf, 32, 64);
      gg += __shfl_xor(gg, 32, 64);
      go += __shfl_xor(go, 32, 64);
      gi += x0; gf += x1; gg += x2; go += x3;
      c = sigf(gf) * c + sigf(gi) * tanh_fast(gg);
      float h = sigf(go) * tanh_fast(c);
      if (l < 32) {                     // q=0 half writes (q=1 identical)
        _Float16 hf = (_Float16)h;
        hh[cur ^ 1][dim] = __builtin_bit_cast(unsigned short, hf);
        if (phase) hs[(b * 128 + t) * 256 + dim] = f2bf(h);
      }
      __syncthreads();                  // h(t) visible; ONE barrier per step
      cur ^= 1;
    }
  }
}

// ---------------------------------------------------------------------------
// FC: logits for hs row m = b*128+t -> out[b][t+1][:]. t=127 rows masked.
// Bs-only LDS (34.8 KB) -> 4 blocks/CU; A fragments straight from L2-hot hs.
// Epilogue: two 64-row half-tiles through Ct[64][132] overlay -> full-512B
// nt stores. grid(32, 250): rb = x, nb = y.
__global__ __launch_bounds__(256, 4) void fc_gemm(
    const unsigned short* __restrict__ hsb, const unsigned short* __restrict__ fwb,
    const float* __restrict__ fcb, float* __restrict__ out) {
  __shared__ __align__(16) char smem[34816];
  typedef unsigned short usrow[136];              // 272B stride
  usrow* Bs = (usrow*)smem;                       // [128][136] = 34816B
  const int tid = threadIdx.x;
  const int rb = blockIdx.x, nb = blockIdx.y;
  const int lane = tid & 63, w = tid >> 6;
  const int wr = w >> 1, wc = w & 1;
  const int fr = lane & 15, kg = lane >> 4;
  f32x4 acc[4][4];
  const f32x4 zero = {0.f, 0.f, 0.f, 0.f};
#pragma unroll
  for (int mi = 0; mi < 4; ++mi)
#pragma unroll
    for (int ni = 0; ni < 4; ++ni) acc[mi][ni] = zero;

  const int lr = tid >> 1, half = tid & 1;
  // per-lane A row base: rows rb*128 + wr*64 + mi*16 + fr  (mi stride 16*256)
  const unsigned short* arow = hsb + (rb * 128 + wr * 64 + fr) * 256;
#pragma unroll
  for (int p = 0; p < 2; ++p) {
    {   // stage B K-half: 128 rows x 128 cols
      const u16x8* s2 = (const u16x8*)(fwb + (nb * 128 + lr) * 256 + p * 128 + half * 64);
      u16x8* d2 = (u16x8*)&Bs[lr][half * 64];
#pragma unroll
      for (int i = 0; i < 8; ++i) d2[i] = s2[i];
    }
    __syncthreads();
#pragma unroll
    for (int ks = 0; ks < 4; ++ks) {
      const int kb = ks * 32 + kg * 8;
      bf16x8 a[4], b[4];
#pragma unroll
      for (int mi = 0; mi < 4; ++mi)
        a[mi] = *(const bf16x8*)(arow + mi * 4096 + p * 128 + kb);
#pragma unroll
      for (int ni = 0; ni < 4; ++ni)
        b[ni] = *(const bf16x8*)&Bs[wc * 64 + ni * 16 + fr][kb];
#pragma unroll
      for (int mi = 0; mi < 4; ++mi)
#pragma unroll
        for (int ni = 0; ni < 4; ++ni)
          acc[mi][ni] = __builtin_amdgcn_mfma_f32_16x16x32_bf16(a[mi], b[ni], acc[mi][ni], 0, 0, 0);
    }
    __syncthreads();   // Bs reads done before next stage / Ct overlay
  }
  // ---- epilogue: two 64-row half-tiles via Ct overlay, nt stores ----
  float bvv[4];
#pragma unroll
  for (int ni = 0; ni < 4; ++ni) bvv[ni] = fcb[nb * 128 + wc * 64 + ni * 16 + fr];
  typedef float frow[132];                        // +4 f32 pad
  frow* Ct = (frow*)smem;                         // [64][132] = 33792B
  const int rr = tid >> 5, cc = (tid & 31) * 4;
#pragma unroll
  for (int hh2 = 0; hh2 < 2; ++hh2) {
    if (wr == hh2) {                   // this wave's rows live in this half
#pragma unroll
      for (int ni = 0; ni < 4; ++ni)
#pragma unroll
        for (int mi = 0; mi < 4; ++mi)
#pragma unroll
          for (int r = 0; r < 4; ++r)
            Ct[mi * 16 + kg * 4 + r][wc * 64 + ni * 16 + fr] = acc[mi][ni][r] + bvv[ni];
    }
    __syncthreads();                   // Ct half complete
#pragma unroll
    for (int pp = 0; pp < 8; ++pp) {
      int r = pp * 8 + rr;             // 0..63 within half
      int tg = hh2 * 64 + r;           // tile row = t (b == rb)
      if (tg != 127) {                 // t=127 is padding
        float* dst = out + (size_t)(rb * 128 + tg + 1) * 32000 + nb * 128 + cc;
        f32x4 v = *(const f32x4*)&Ct[r][cc];
        __builtin_nontemporal_store(v, (f32x4*)dst);
      }
    }
    __syncthreads();                   // stores read Ct before next overwrite
  }
}

// ---------------------------------------------------------------------------
extern "C" void kernel_launch(void* const* d_in, const int* in_sizes, int n_in,
                              void* d_out, int out_size, void* d_ws, size_t ws_size,
                              hipStream_t stream) {
  const int* src = (const int*)d_in[0];
  const int* tgt = (const int*)d_in[1];
  const float* enc_emb = (const float*)d_in[2];
  const float* enc_Wih = (const float*)d_in[3];
  const float* enc_Whh = (const float*)d_in[4];
  const float* enc_b = (const float*)d_in[5];
  const float* dec_emb = (const float*)d_in[6];
  const float* dec_Wih = (const float*)d_in[7];
  const float* dec_Whh = (const float*)d_in[8];
  const float* dec_b = (const float*)d_in[9];
  const float* fc_W = (const float*)d_in[10];
  const float* fc_b = (const float*)d_in[11];
  float* out = (float*)d_out;
  char* ws = (char*)d_ws;

  float* xg_e = (float*)(ws + WS_XG_E);
  float* xg_d = (float*)(ws + WS_XG_D);
  unsigned short* fcw = (unsigned short*)(ws + WS_FCW);
  unsigned short* hs = (unsigned short*)(ws + WS_HS);
  unsigned short* wte = (unsigned short*)(ws + WS_WTE);
  unsigned short* wtd = (unsigned short*)(ws + WS_WTD);

  zero_col0<<<1000, 256, 0, stream>>>(out);
  cvt_bf16<<<8000, 256, 0, stream>>>(fc_W, fcw, 2048000);
  prep_whalf<<<dim3(1024, 2), 256, 0, stream>>>(enc_Whh, dec_Whh, wte, wtd);
  xg_gemm<<<dim3(8, 32), 256, 0, stream>>>(src, enc_emb, enc_Wih, enc_b, xg_e, 4096);
  xg_gemm<<<dim3(8, 32), 256, 0, stream>>>(tgt, dec_emb, dec_Wih, dec_b, xg_d, 4064);
  lstm_batch<<<32, 512, 0, stream>>>(wte, wtd, xg_e, xg_d, hs);
  fc_gemm<<<dim3(32, 250), 256, 0, stream>>>(hs, fcw, fc_b, out);
}

// Round 16
// 677.879 us; speedup vs baseline: 1.0772x; 1.0772x over previous
//
#include <hip/hip_runtime.h>

// ---------------------------------------------------------------------------
// Seq2Seq: encoder LSTM (128 steps) -> decoder LSTM (127 steps) -> FC to vocab
// B=32, S=T=128, V=32000, E=H=256
//
// R16 = R14 verbatim (best measured: 678.8 us). R15's fc-at-4-blocks/CU
// regressed (global-A scattered loads + doubled epilogue barriers); R13's
// 2-row lstm regressed (halved active CUs); fusion (R10-12) never beat the
// split. Composition: R9 lstm (32 blocks x 1 row, weights CU-resident,
// 1 barrier/step) + R13 fc (K-split staging, 69.6 KB LDS, 2 blocks/CU).
// ---------------------------------------------------------------------------

typedef __attribute__((ext_vector_type(8))) short bf16x8;
typedef __attribute__((ext_vector_type(4))) float f32x4;
typedef __attribute__((ext_vector_type(8))) unsigned short u16x8;
typedef __attribute__((ext_vector_type(4))) unsigned int u32x4;
typedef __attribute__((ext_vector_type(8))) _Float16 f16x8;
typedef __attribute__((ext_vector_type(2))) _Float16 h2;

// workspace byte offsets (all 256-aligned)
#define WS_XG_E   0u          // 128*32*1024 f32 = 16,777,216 B
#define WS_XG_D   16777216u   // 127*32*1024 f32 = 16,646,144 B
#define WS_FCW    33423360u   // 32000*256 bf16  = 16,384,000 B
#define WS_HS     49807360u   // 4096*256 bf16   =  2,097,152 B (padded [b*128+t])
#define WS_WTE    51904512u   // 1024*256 f16    =    524,288 B
#define WS_WTD    52428800u   // 1024*256 f16    =    524,288 B

#define KC_REG 48   // weight chunks in registers (gates i,f,g)
#define KC_LDS 16   // weight chunks in LDS (gate o) = 128 KB

__device__ __forceinline__ unsigned short f2bf(float f) {
  unsigned u = __float_as_uint(f);
  u += 0x7FFFu + ((u >> 16) & 1u);   // round-to-nearest-even
  return (unsigned short)(u >> 16);
}

__device__ __forceinline__ float sigf(float x) {
  float e = __expf(-x);
  return __builtin_amdgcn_rcpf(1.f + e);
}
__device__ __forceinline__ float tanh_fast(float x) {
  float e = __expf(-2.f * x);
  return fmaf(2.f, __builtin_amdgcn_rcpf(1.f + e), -1.f);  // (1-e)/(1+e)
}

#if __has_builtin(__builtin_amdgcn_fdot2)
#define FDOT2(a, w, h) a = __builtin_amdgcn_fdot2(w, h, a, false)
#else
#define FDOT2(a, w, h) a = fmaf((float)w[0], (float)h[0], fmaf((float)w[1], (float)h[1], a))
#endif

// 8 f16 weights vs 8 f16 h values -> two accumulator chains
__device__ __forceinline__ void dot8(const u16x8 w, const u32x4 hbits,
                                     float& a0, float& a1) {
  f16x8 wv = __builtin_bit_cast(f16x8, w);
  f16x8 hv = __builtin_bit_cast(f16x8, hbits);
  h2 w0 = {wv[0], wv[1]}, w1 = {wv[2], wv[3]};
  h2 w2 = {wv[4], wv[5]}, w3 = {wv[6], wv[7]};
  h2 h0 = {hv[0], hv[1]}, h1 = {hv[2], hv[3]};
  h2 hc = {hv[4], hv[5]}, h3 = {hv[6], hv[7]};
  FDOT2(a0, w0, h0);
  FDOT2(a1, w1, h1);
  FDOT2(a0, w2, hc);
  FDOT2(a1, w3, h3);
}

// ---------------------------------------------------------------------------
__global__ __launch_bounds__(256) void zero_col0(float* __restrict__ out) {
  int i = blockIdx.x * 256 + threadIdx.x;        // 256,000 float4s total
  int b = i / 8000;
  int r = i - b * 8000;
  f32x4 z = {0.f, 0.f, 0.f, 0.f};
  __builtin_nontemporal_store(z, (f32x4*)out + b * 1024000 + r);
}

__global__ __launch_bounds__(256) void cvt_bf16(const float* __restrict__ in,
                                                unsigned short* __restrict__ o,
                                                int n4) {
  int i = blockIdx.x * 256 + threadIdx.x;
  if (i < n4) {
    float4 v = ((const float4*)in)[i];
    ushort4 u;
    u.x = f2bf(v.x); u.y = f2bf(v.y); u.z = f2bf(v.z); u.w = f2bf(v.w);
    *(ushort4*)(o + i * 4) = u;
  }
}

// Whh[1024 r][256 k] -> f16 T[chunk j][512 tid][8 e], j = gate*16 + kk.
// Thread tid = w*64+l owns dim = w*32+(l&31), k-half q = l>>5; chunk (gate,kk)
// covers k = q*128 + kk*8 .. +8 of row gate*256+dim.
__global__ __launch_bounds__(256) void prep_whalf(const float* __restrict__ We,
                                                  const float* __restrict__ Wd,
                                                  unsigned short* __restrict__ Te,
                                                  unsigned short* __restrict__ Td) {
  int d = blockIdx.x * 256 + threadIdx.x;       // 0..262143
  const float* W = blockIdx.y ? Wd : We;
  unsigned short* T = blockIdx.y ? Td : Te;
  int e = d & 7;
  int tmp = d >> 3;
  int tidb = tmp & 511;
  int j = tmp >> 9;                 // 0..63
  int gg = j >> 4, kk = j & 15;
  int wv = tidb >> 6, ln = tidb & 63;
  int qq = ln >> 5, dm = wv * 32 + (ln & 31);
  _Float16 v = (_Float16)W[(gg * 256 + dm) * 256 + qq * 128 + kk * 8 + e];
  T[d] = __builtin_bit_cast(unsigned short, v);
}

// ---------------------------------------------------------------------------
// xg[row][n] = emb[token(row)] @ Wih^T + bias ; row = t*32 + b
__global__ __launch_bounds__(256) void xg_gemm(
    const int* __restrict__ tok, const float* __restrict__ emb,
    const float* __restrict__ Wih, const float* __restrict__ bias,
    float* __restrict__ xg, const int Mrows) {
  __shared__ unsigned short As[128][264];  // +8 bf16 pad -> 2-way (free)
  __shared__ unsigned short Bs[128][264];
  const int tid = threadIdx.x;
  const int nb = blockIdx.x, rb = blockIdx.y;
  {
    int lr = tid >> 1, half = tid & 1;
    int cb = half * 128;
    int row = rb * 128 + lr;
    int rowc = row < Mrows ? row : (Mrows - 1);
    int tt = rowc >> 5, bb = rowc & 31;
    int tk = tok[bb * 128 + tt];
    const float4* sa = (const float4*)(emb + tk * 256 + cb);
    const float4* sb = (const float4*)(Wih + (nb * 128 + lr) * 256 + cb);
#pragma unroll
    for (int i = 0; i < 32; ++i) {
      float4 v = sa[i];
      ushort4 u;
      u.x = f2bf(v.x); u.y = f2bf(v.y); u.z = f2bf(v.z); u.w = f2bf(v.w);
      *(ushort4*)&As[lr][cb + i * 4] = u;
      float4 v2 = sb[i];
      ushort4 u2;
      u2.x = f2bf(v2.x); u2.y = f2bf(v2.y); u2.z = f2bf(v2.z); u2.w = f2bf(v2.w);
      *(ushort4*)&Bs[lr][cb + i * 4] = u2;
    }
  }
  __syncthreads();
  const int lane = tid & 63, w = tid >> 6;
  const int wr = w >> 1, wc = w & 1;
  const int fr = lane & 15, kg = lane >> 4;
  f32x4 acc[4][4];
  const f32x4 zero = {0.f, 0.f, 0.f, 0.f};
#pragma unroll
  for (int mi = 0; mi < 4; ++mi)
#pragma unroll
    for (int ni = 0; ni < 4; ++ni) acc[mi][ni] = zero;
#pragma unroll
  for (int ks = 0; ks < 8; ++ks) {
    const int kb = ks * 32 + kg * 8;
    bf16x8 a[4], b[4];
#pragma unroll
    for (int mi = 0; mi < 4; ++mi)
      a[mi] = *(const bf16x8*)&As[wr * 64 + mi * 16 + fr][kb];
#pragma unroll
    for (int ni = 0; ni < 4; ++ni)
      b[ni] = *(const bf16x8*)&Bs[wc * 64 + ni * 16 + fr][kb];
#pragma unroll
    for (int mi = 0; mi < 4; ++mi)
#pragma unroll
      for (int ni = 0; ni < 4; ++ni)
        acc[mi][ni] = __builtin_amdgcn_mfma_f32_16x16x32_bf16(a[mi], b[ni], acc[mi][ni], 0, 0, 0);
  }
#pragma unroll
  for (int ni = 0; ni < 4; ++ni) {
    const int colg = nb * 128 + wc * 64 + ni * 16 + fr;
    const float bv = bias[colg];
#pragma unroll
    for (int mi = 0; mi < 4; ++mi) {
#pragma unroll
      for (int r = 0; r < 4; ++r) {
        int rowg = rb * 128 + wr * 64 + mi * 16 + kg * 4 + r;
        if (rowg < Mrows) xg[rowg * 1024 + colg] = acc[mi][ni][r] + bv;
      }
    }
  }
}

// ---------------------------------------------------------------------------
// Per-batch LSTM chain (R9). Block b (32 blocks x 512 thr, 1 block/CU).
// Lane l of wave w: dim = w*32+(l&31), k-half q = l>>5, owns gates i,f,g,o of
// that dim over its k-half. Gate reduce: one __shfl_xor(32). h double-buffered
// in LDS (1 barrier/step). Weights: i,f,g in 48 u16x8 regs; o in 128 KB LDS.
__global__ __launch_bounds__(512, 2) void lstm_batch(
    const unsigned short* __restrict__ WTe, const unsigned short* __restrict__ WTd,
    const float* __restrict__ xgE, const float* __restrict__ xgD,
    unsigned short* __restrict__ hs) {
  __shared__ __align__(16) unsigned short hh[2][256];        // h as f16, dbuf
  __shared__ __align__(16) unsigned short wl[KC_LDS * 4096]; // 128 KB (o gate)
  const int tid = threadIdx.x;   // 0..511
  const int b = blockIdx.x;
  const int l = tid & 63, w = tid >> 6;
  const int q = l >> 5;                 // k-half
  const int dim = w * 32 + (l & 31);
  float c = 0.f;
  int cur = 0;
  if (tid < 256) hh[0][tid] = 0;        // h0 = 0 (f16 zero bits)

  for (int phase = 0; phase < 2; ++phase) {
    const unsigned short* WT = phase ? WTd : WTe;
    const float* xg = phase ? xgD : xgE;
    const int steps = phase ? 127 : 128;
    const u16x8* wsrc = (const u16x8*)WT + tid;
    u16x8 wr[KC_REG];
#pragma unroll
    for (int j = 0; j < KC_REG; ++j) wr[j] = wsrc[j * 512];
    __syncthreads();   // prev phase's wl reads complete before overwrite
    {
      u16x8* ld = (u16x8*)wl + tid;
#pragma unroll
      for (int j = 0; j < KC_LDS; ++j) ld[j * 512] = wsrc[(KC_REG + j) * 512];
    }
    __syncthreads();   // wl + hh visible

    for (int t = 0; t < steps; ++t) {
      const float* xr = xg + (t * 32 + b) * 1024 + dim;
      float x0 = xr[0], x1 = xr[256], x2 = xr[512], x3 = xr[768];
      const u32x4* hq = (const u32x4*)&hh[cur][q * 128];
      const u16x8* wlp = (const u16x8*)wl + tid;
      float ai0 = 0.f, ai1 = 0.f, af0 = 0.f, af1 = 0.f;
      float ag0 = 0.f, ag1 = 0.f, ao0 = 0.f, ao1 = 0.f;
#pragma unroll
      for (int kk = 0; kk < 16; ++kk) {
        u32x4 hv = hq[kk];
        dot8(wr[kk],        hv, ai0, ai1);
        dot8(wr[16 + kk],   hv, af0, af1);
        dot8(wr[32 + kk],   hv, ag0, ag1);
        dot8(wlp[kk * 512], hv, ao0, ao1);
      }
      float gi = ai0 + ai1, gf = af0 + af1;
      float gg = ag0 + ag1, go = ao0 + ao1;
      gi += __shfl_xor(gi, 32, 64);     // combine k-halves (butterfly)
      gf += __shfl_xor(gf, 32, 64);
      gg += __shfl_xor(gg, 32, 64);
      go += __shfl_xor(go, 32, 64);
      gi += x0; gf += x1; gg += x2; go += x3;
      c = sigf(gf) * c + sigf(gi) * tanh_fast(gg);
      float h = sigf(go) * tanh_fast(c);
      if (l < 32) {                     // q=0 half writes (q=1 identical)
        _Float16 hf = (_Float16)h;
        hh[cur ^ 1][dim] = __builtin_bit_cast(unsigned short, hf);
        if (phase) hs[(b * 128 + t) * 256 + dim] = f2bf(h);
      }
      __syncthreads();                  // h(t) visible; ONE barrier per step
      cur ^= 1;
    }
  }
}

// ---------------------------------------------------------------------------
// FC: logits for hs row m = b*128+t -> out[b][t+1][:]. t=127 rows masked.
// K-split staging: two 128-col passes (As/Bs [128][136] each, 69.6 KB total)
// -> 2 blocks/CU. Epilogue: Ct transpose (overlays As+Bs) -> full-512B nt
// stores. grid(32, 250): rb = x, nb = y.
__global__ __launch_bounds__(256) void fc_gemm(
    const unsigned short* __restrict__ hsb, const unsigned short* __restrict__ fwb,
    const float* __restrict__ fcb, float* __restrict__ out) {
  __shared__ __align__(16) char smem[69632];
  typedef unsigned short usrow[136];              // 272B stride
  usrow* As = (usrow*)smem;                       // [128][136] @ 0     (34816B)
  usrow* Bs = (usrow*)(smem + 34816);             // [128][136]         (34816B)
  const int tid = threadIdx.x;
  const int rb = blockIdx.x, nb = blockIdx.y;
  const int lane = tid & 63, w = tid >> 6;
  const int wr = w >> 1, wc = w & 1;
  const int fr = lane & 15, kg = lane >> 4;
  f32x4 acc[4][4];
  const f32x4 zero = {0.f, 0.f, 0.f, 0.f};
#pragma unroll
  for (int mi = 0; mi < 4; ++mi)
#pragma unroll
    for (int ni = 0; ni < 4; ++ni) acc[mi][ni] = zero;

  const int lr = tid >> 1, half = tid & 1;
#pragma unroll
  for (int p = 0; p < 2; ++p) {
    {   // stage this K-half: 128 rows x 128 cols each of A and B
      const u16x8* s = (const u16x8*)(hsb + (rb * 128 + lr) * 256 + p * 128 + half * 64);
      const u16x8* s2 = (const u16x8*)(fwb + (nb * 128 + lr) * 256 + p * 128 + half * 64);
      u16x8* d = (u16x8*)&As[lr][half * 64];
      u16x8* d2 = (u16x8*)&Bs[lr][half * 64];
#pragma unroll
      for (int i = 0; i < 8; ++i) { d[i] = s[i]; d2[i] = s2[i]; }
    }
    __syncthreads();
#pragma unroll
    for (int ks = 0; ks < 4; ++ks) {
      const int kb = ks * 32 + kg * 8;
      bf16x8 a[4], b[4];
#pragma unroll
      for (int mi = 0; mi < 4; ++mi)
        a[mi] = *(const bf16x8*)&As[wr * 64 + mi * 16 + fr][kb];
#pragma unroll
      for (int ni = 0; ni < 4; ++ni)
        b[ni] = *(const bf16x8*)&Bs[wc * 64 + ni * 16 + fr][kb];
#pragma unroll
      for (int mi = 0; mi < 4; ++mi)
#pragma unroll
        for (int ni = 0; ni < 4; ++ni)
          acc[mi][ni] = __builtin_amdgcn_mfma_f32_16x16x32_bf16(a[mi], b[ni], acc[mi][ni], 0, 0, 0);
    }
    __syncthreads();   // all reads done before next stage / Ct overlay
  }
  // ---- epilogue: transpose through LDS (overlays As+Bs), nt stores ----
  typedef float frow[132];                        // +4 f32 pad
  frow* Ct = (frow*)smem;                         // [128][132] = 67584B
#pragma unroll
  for (int ni = 0; ni < 4; ++ni) {
    const int cl = wc * 64 + ni * 16 + fr;
    const float bv = fcb[nb * 128 + cl];
#pragma unroll
    for (int mi = 0; mi < 4; ++mi) {
#pragma unroll
      for (int r = 0; r < 4; ++r)
        Ct[wr * 64 + mi * 16 + kg * 4 + r][cl] = acc[mi][ni][r] + bv;
    }
  }
  __syncthreads();
  // 256 thr: cc=(tid&31)*4 floats (16B), rr=tid>>5 (0..7); per instruction a
  // wave covers 2 rows x 512B contiguous -> every 64B sector fully written.
  const int rr = tid >> 5, cc = (tid & 31) * 4;
#pragma unroll
  for (int p = 0; p < 16; ++p) {
    int r = p * 8 + rr;                           // tile row = t (b == rb)
    if (r != 127) {                               // t=127 is padding
      float* dst = out + (size_t)(rb * 128 + r + 1) * 32000 + nb * 128 + cc;
      f32x4 v = *(const f32x4*)&Ct[r][cc];
      __builtin_nontemporal_store(v, (f32x4*)dst);
    }
  }
}

// ---------------------------------------------------------------------------
extern "C" void kernel_launch(void* const* d_in, const int* in_sizes, int n_in,
                              void* d_out, int out_size, void* d_ws, size_t ws_size,
                              hipStream_t stream) {
  const int* src = (const int*)d_in[0];
  const int* tgt = (const int*)d_in[1];
  const float* enc_emb = (const float*)d_in[2];
  const float* enc_Wih = (const float*)d_in[3];
  const float* enc_Whh = (const float*)d_in[4];
  const float* enc_b = (const float*)d_in[5];
  const float* dec_emb = (const float*)d_in[6];
  const float* dec_Wih = (const float*)d_in[7];
  const float* dec_Whh = (const float*)d_in[8];
  const float* dec_b = (const float*)d_in[9];
  const float* fc_W = (const float*)d_in[10];
  const float* fc_b = (const float*)d_in[11];
  float* out = (float*)d_out;
  char* ws = (char*)d_ws;

  float* xg_e = (float*)(ws + WS_XG_E);
  float* xg_d = (float*)(ws + WS_XG_D);
  unsigned short* fcw = (unsigned short*)(ws + WS_FCW);
  unsigned short* hs = (unsigned short*)(ws + WS_HS);
  unsigned short* wte = (unsigned short*)(ws + WS_WTE);
  unsigned short* wtd = (unsigned short*)(ws + WS_WTD);

  zero_col0<<<1000, 256, 0, stream>>>(out);
  cvt_bf16<<<8000, 256, 0, stream>>>(fc_W, fcw, 2048000);
  prep_whalf<<<dim3(1024, 2), 256, 0, stream>>>(enc_Whh, dec_Whh, wte, wtd);
  xg_gemm<<<dim3(8, 32), 256, 0, stream>>>(src, enc_emb, enc_Wih, enc_b, xg_e, 4096);
  xg_gemm<<<dim3(8, 32), 256, 0, stream>>>(tgt, dec_emb, dec_Wih, dec_b, xg_d, 4064);
  lstm_batch<<<32, 512, 0, stream>>>(wte, wtd, xg_e, xg_d, hs);
  fc_gemm<<<dim3(32, 250), 256, 0, stream>>>(hs, fcw, fc_b, out);
}

// Round 17
// 662.292 us; speedup vs baseline: 1.1026x; 1.0235x over previous
//
#include <hip/hip_runtime.h>

// ---------------------------------------------------------------------------
// Seq2Seq: encoder LSTM (128 steps) -> decoder LSTM (127 steps) -> FC to vocab
// B=32, S=T=128, V=32000, E=H=256
//
// R17 = R14/R16 with fc retiled 64x128 @ 3 blocks/CU (52.2 KB LDS: A 17.4 KB
// + B 34.8 KB, K-split staging, Ct[64][132] overlay, full-512B nt stores) --
// store drain now hides under 2 other blocks' MFMA. zero_col0 folded into
// fc: the masked tg==127 store slot writes zeros to out[b][0][.] instead.
// lstm (R9 structure) untouched.
// ---------------------------------------------------------------------------

typedef __attribute__((ext_vector_type(8))) short bf16x8;
typedef __attribute__((ext_vector_type(4))) float f32x4;
typedef __attribute__((ext_vector_type(8))) unsigned short u16x8;
typedef __attribute__((ext_vector_type(4))) unsigned int u32x4;
typedef __attribute__((ext_vector_type(8))) _Float16 f16x8;
typedef __attribute__((ext_vector_type(2))) _Float16 h2;

// workspace byte offsets (all 256-aligned)
#define WS_XG_E   0u          // 128*32*1024 f32 = 16,777,216 B
#define WS_XG_D   16777216u   // 127*32*1024 f32 = 16,646,144 B
#define WS_FCW    33423360u   // 32000*256 bf16  = 16,384,000 B
#define WS_HS     49807360u   // 4096*256 bf16   =  2,097,152 B (padded [b*128+t])
#define WS_WTE    51904512u   // 1024*256 f16    =    524,288 B
#define WS_WTD    52428800u   // 1024*256 f16    =    524,288 B

#define KC_REG 48   // weight chunks in registers (gates i,f,g)
#define KC_LDS 16   // weight chunks in LDS (gate o) = 128 KB

__device__ __forceinline__ unsigned short f2bf(float f) {
  unsigned u = __float_as_uint(f);
  u += 0x7FFFu + ((u >> 16) & 1u);   // round-to-nearest-even
  return (unsigned short)(u >> 16);
}

__device__ __forceinline__ float sigf(float x) {
  float e = __expf(-x);
  return __builtin_amdgcn_rcpf(1.f + e);
}
__device__ __forceinline__ float tanh_fast(float x) {
  float e = __expf(-2.f * x);
  return fmaf(2.f, __builtin_amdgcn_rcpf(1.f + e), -1.f);  // (1-e)/(1+e)
}

#if __has_builtin(__builtin_amdgcn_fdot2)
#define FDOT2(a, w, h) a = __builtin_amdgcn_fdot2(w, h, a, false)
#else
#define FDOT2(a, w, h) a = fmaf((float)w[0], (float)h[0], fmaf((float)w[1], (float)h[1], a))
#endif

// 8 f16 weights vs 8 f16 h values -> two accumulator chains
__device__ __forceinline__ void dot8(const u16x8 w, const u32x4 hbits,
                                     float& a0, float& a1) {
  f16x8 wv = __builtin_bit_cast(f16x8, w);
  f16x8 hv = __builtin_bit_cast(f16x8, hbits);
  h2 w0 = {wv[0], wv[1]}, w1 = {wv[2], wv[3]};
  h2 w2 = {wv[4], wv[5]}, w3 = {wv[6], wv[7]};
  h2 h0 = {hv[0], hv[1]}, h1 = {hv[2], hv[3]};
  h2 hc = {hv[4], hv[5]}, h3 = {hv[6], hv[7]};
  FDOT2(a0, w0, h0);
  FDOT2(a1, w1, h1);
  FDOT2(a0, w2, hc);
  FDOT2(a1, w3, h3);
}

// ---------------------------------------------------------------------------
__global__ __launch_bounds__(256) void cvt_bf16(const float* __restrict__ in,
                                                unsigned short* __restrict__ o,
                                                int n4) {
  int i = blockIdx.x * 256 + threadIdx.x;
  if (i < n4) {
    float4 v = ((const float4*)in)[i];
    ushort4 u;
    u.x = f2bf(v.x); u.y = f2bf(v.y); u.z = f2bf(v.z); u.w = f2bf(v.w);
    *(ushort4*)(o + i * 4) = u;
  }
}

// Whh[1024 r][256 k] -> f16 T[chunk j][512 tid][8 e], j = gate*16 + kk.
__global__ __launch_bounds__(256) void prep_whalf(const float* __restrict__ We,
                                                  const float* __restrict__ Wd,
                                                  unsigned short* __restrict__ Te,
                                                  unsigned short* __restrict__ Td) {
  int d = blockIdx.x * 256 + threadIdx.x;       // 0..262143
  const float* W = blockIdx.y ? Wd : We;
  unsigned short* T = blockIdx.y ? Td : Te;
  int e = d & 7;
  int tmp = d >> 3;
  int tidb = tmp & 511;
  int j = tmp >> 9;                 // 0..63
  int gg = j >> 4, kk = j & 15;
  int wv = tidb >> 6, ln = tidb & 63;
  int qq = ln >> 5, dm = wv * 32 + (ln & 31);
  _Float16 v = (_Float16)W[(gg * 256 + dm) * 256 + qq * 128 + kk * 8 + e];
  T[d] = __builtin_bit_cast(unsigned short, v);
}

// ---------------------------------------------------------------------------
// xg[row][n] = emb[token(row)] @ Wih^T + bias ; row = t*32 + b
__global__ __launch_bounds__(256) void xg_gemm(
    const int* __restrict__ tok, const float* __restrict__ emb,
    const float* __restrict__ Wih, const float* __restrict__ bias,
    float* __restrict__ xg, const int Mrows) {
  __shared__ unsigned short As[128][264];  // +8 bf16 pad -> 2-way (free)
  __shared__ unsigned short Bs[128][264];
  const int tid = threadIdx.x;
  const int nb = blockIdx.x, rb = blockIdx.y;
  {
    int lr = tid >> 1, half = tid & 1;
    int cb = half * 128;
    int row = rb * 128 + lr;
    int rowc = row < Mrows ? row : (Mrows - 1);
    int tt = rowc >> 5, bb = rowc & 31;
    int tk = tok[bb * 128 + tt];
    const float4* sa = (const float4*)(emb + tk * 256 + cb);
    const float4* sb = (const float4*)(Wih + (nb * 128 + lr) * 256 + cb);
#pragma unroll
    for (int i = 0; i < 32; ++i) {
      float4 v = sa[i];
      ushort4 u;
      u.x = f2bf(v.x); u.y = f2bf(v.y); u.z = f2bf(v.z); u.w = f2bf(v.w);
      *(ushort4*)&As[lr][cb + i * 4] = u;
      float4 v2 = sb[i];
      ushort4 u2;
      u2.x = f2bf(v2.x); u2.y = f2bf(v2.y); u2.z = f2bf(v2.z); u2.w = f2bf(v2.w);
      *(ushort4*)&Bs[lr][cb + i * 4] = u2;
    }
  }
  __syncthreads();
  const int lane = tid & 63, w = tid >> 6;
  const int wr = w >> 1, wc = w & 1;
  const int fr = lane & 15, kg = lane >> 4;
  f32x4 acc[4][4];
  const f32x4 zero = {0.f, 0.f, 0.f, 0.f};
#pragma unroll
  for (int mi = 0; mi < 4; ++mi)
#pragma unroll
    for (int ni = 0; ni < 4; ++ni) acc[mi][ni] = zero;
#pragma unroll
  for (int ks = 0; ks < 8; ++ks) {
    const int kb = ks * 32 + kg * 8;
    bf16x8 a[4], b[4];
#pragma unroll
    for (int mi = 0; mi < 4; ++mi)
      a[mi] = *(const bf16x8*)&As[wr * 64 + mi * 16 + fr][kb];
#pragma unroll
    for (int ni = 0; ni < 4; ++ni)
      b[ni] = *(const bf16x8*)&Bs[wc * 64 + ni * 16 + fr][kb];
#pragma unroll
    for (int mi = 0; mi < 4; ++mi)
#pragma unroll
      for (int ni = 0; ni < 4; ++ni)
        acc[mi][ni] = __builtin_amdgcn_mfma_f32_16x16x32_bf16(a[mi], b[ni], acc[mi][ni], 0, 0, 0);
  }
#pragma unroll
  for (int ni = 0; ni < 4; ++ni) {
    const int colg = nb * 128 + wc * 64 + ni * 16 + fr;
    const float bv = bias[colg];
#pragma unroll
    for (int mi = 0; mi < 4; ++mi) {
#pragma unroll
      for (int r = 0; r < 4; ++r) {
        int rowg = rb * 128 + wr * 64 + mi * 16 + kg * 4 + r;
        if (rowg < Mrows) xg[rowg * 1024 + colg] = acc[mi][ni][r] + bv;
      }
    }
  }
}

// ---------------------------------------------------------------------------
// Per-batch LSTM chain (R9). Block b (32 blocks x 512 thr, 1 block/CU).
// Lane l of wave w: dim = w*32+(l&31), k-half q = l>>5, owns gates i,f,g,o of
// that dim over its k-half. Gate reduce: one __shfl_xor(32). h double-buffered
// in LDS (1 barrier/step). Weights: i,f,g in 48 u16x8 regs; o in 128 KB LDS.
__global__ __launch_bounds__(512, 2) void lstm_batch(
    const unsigned short* __restrict__ WTe, const unsigned short* __restrict__ WTd,
    const float* __restrict__ xgE, const float* __restrict__ xgD,
    unsigned short* __restrict__ hs) {
  __shared__ __align__(16) unsigned short hh[2][256];        // h as f16, dbuf
  __shared__ __align__(16) unsigned short wl[KC_LDS * 4096]; // 128 KB (o gate)
  const int tid = threadIdx.x;   // 0..511
  const int b = blockIdx.x;
  const int l = tid & 63, w = tid >> 6;
  const int q = l >> 5;                 // k-half
  const int dim = w * 32 + (l & 31);
  float c = 0.f;
  int cur = 0;
  if (tid < 256) hh[0][tid] = 0;        // h0 = 0 (f16 zero bits)

  for (int phase = 0; phase < 2; ++phase) {
    const unsigned short* WT = phase ? WTd : WTe;
    const float* xg = phase ? xgD : xgE;
    const int steps = phase ? 127 : 128;
    const u16x8* wsrc = (const u16x8*)WT + tid;
    u16x8 wr[KC_REG];
#pragma unroll
    for (int j = 0; j < KC_REG; ++j) wr[j] = wsrc[j * 512];
    __syncthreads();   // prev phase's wl reads complete before overwrite
    {
      u16x8* ld = (u16x8*)wl + tid;
#pragma unroll
      for (int j = 0; j < KC_LDS; ++j) ld[j * 512] = wsrc[(KC_REG + j) * 512];
    }
    __syncthreads();   // wl + hh visible

    for (int t = 0; t < steps; ++t) {
      const float* xr = xg + (t * 32 + b) * 1024 + dim;
      float x0 = xr[0], x1 = xr[256], x2 = xr[512], x3 = xr[768];
      const u32x4* hq = (const u32x4*)&hh[cur][q * 128];
      const u16x8* wlp = (const u16x8*)wl + tid;
      float ai0 = 0.f, ai1 = 0.f, af0 = 0.f, af1 = 0.f;
      float ag0 = 0.f, ag1 = 0.f, ao0 = 0.f, ao1 = 0.f;
#pragma unroll
      for (int kk = 0; kk < 16; ++kk) {
        u32x4 hv = hq[kk];
        dot8(wr[kk],        hv, ai0, ai1);
        dot8(wr[16 + kk],   hv, af0, af1);
        dot8(wr[32 + kk],   hv, ag0, ag1);
        dot8(wlp[kk * 512], hv, ao0, ao1);
      }
      float gi = ai0 + ai1, gf = af0 + af1;
      float gg = ag0 + ag1, go = ao0 + ao1;
      gi += __shfl_xor(gi, 32, 64);     // combine k-halves (butterfly)
      gf += __shfl_xor(gf, 32, 64);
      gg += __shfl_xor(gg, 32, 64);
      go += __shfl_xor(go, 32, 64);
      gi += x0; gf += x1; gg += x2; go += x3;
      c = sigf(gf) * c + sigf(gi) * tanh_fast(gg);
      float h = sigf(go) * tanh_fast(c);
      if (l < 32) {                     // q=0 half writes (q=1 identical)
        _Float16 hf = (_Float16)h;
        hh[cur ^ 1][dim] = __builtin_bit_cast(unsigned short, hf);
        if (phase) hs[(b * 128 + t) * 256 + dim] = f2bf(h);
      }
      __syncthreads();                  // h(t) visible; ONE barrier per step
      cur ^= 1;
    }
  }
}

// ---------------------------------------------------------------------------
// FC: 64x128 tiles @ 3 blocks/CU. grid(64, 250): rb = 64-row hs tile
// (b = rb>>1, t base = (rb&1)*64), nb = 128-col fcw tile. K-split staging
// (two 128-col passes). Epilogue: Ct[64][132] overlay -> full-512B nt
// stores; the masked tg==127 slot writes zeros to out[b][0][.] instead
// (replaces the zero_col0 kernel).
__global__ __launch_bounds__(256, 3) void fc_gemm(
    const unsigned short* __restrict__ hsb, const unsigned short* __restrict__ fwb,
    const float* __restrict__ fcb, float* __restrict__ out) {
  __shared__ __align__(16) char smem[52224];
  typedef unsigned short usrow[136];              // 272B stride
  usrow* As = (usrow*)smem;                       // [64][136]  = 17408B
  usrow* Bs = (usrow*)(smem + 17408);             // [128][136] = 34816B
  const int tid = threadIdx.x;
  const int rb = blockIdx.x, nb = blockIdx.y;
  const int lane = tid & 63, w = tid >> 6;
  const int wm = w & 1, wn = w >> 1;              // 2 m-tiles x 2 n-tiles
  const int fr = lane & 15, kg = lane >> 4;
  f32x4 acc[2][4];
  const f32x4 zero = {0.f, 0.f, 0.f, 0.f};
#pragma unroll
  for (int mi = 0; mi < 2; ++mi)
#pragma unroll
    for (int ni = 0; ni < 4; ++ni) acc[mi][ni] = zero;

  const int ar = tid >> 2, asg = tid & 3;         // A: 4 thr/row, 32 cols each
  const int br = tid >> 1, bsg = tid & 1;         // B: 2 thr/row, 64 cols each
#pragma unroll
  for (int p = 0; p < 2; ++p) {
    {   // stage this K-half: A 64x128, B 128x128
      const u16x8* s = (const u16x8*)(hsb + (rb * 64 + ar) * 256 + p * 128 + asg * 32);
      u16x8* d = (u16x8*)&As[ar][asg * 32];
#pragma unroll
      for (int i = 0; i < 4; ++i) d[i] = s[i];
      const u16x8* s2 = (const u16x8*)(fwb + (nb * 128 + br) * 256 + p * 128 + bsg * 64);
      u16x8* d2 = (u16x8*)&Bs[br][bsg * 64];
#pragma unroll
      for (int i = 0; i < 8; ++i) d2[i] = s2[i];
    }
    __syncthreads();
#pragma unroll
    for (int ks = 0; ks < 4; ++ks) {
      const int kb = ks * 32 + kg * 8;
      bf16x8 a[2], b[4];
#pragma unroll
      for (int mi = 0; mi < 2; ++mi)
        a[mi] = *(const bf16x8*)&As[wm * 32 + mi * 16 + fr][kb];
#pragma unroll
      for (int ni = 0; ni < 4; ++ni)
        b[ni] = *(const bf16x8*)&Bs[wn * 64 + ni * 16 + fr][kb];
#pragma unroll
      for (int mi = 0; mi < 2; ++mi)
#pragma unroll
        for (int ni = 0; ni < 4; ++ni)
          acc[mi][ni] = __builtin_amdgcn_mfma_f32_16x16x32_bf16(a[mi], b[ni], acc[mi][ni], 0, 0, 0);
    }
    __syncthreads();   // all reads done before next stage / Ct overlay
  }
  // ---- epilogue: transpose through LDS (overlays As+Bs), nt stores ----
  typedef float frow[132];                        // +4 f32 pad
  frow* Ct = (frow*)smem;                         // [64][132] = 33792B
#pragma unroll
  for (int ni = 0; ni < 4; ++ni) {
    const int cl = wn * 64 + ni * 16 + fr;
    const float bv = fcb[nb * 128 + cl];
#pragma unroll
    for (int mi = 0; mi < 2; ++mi) {
#pragma unroll
      for (int r = 0; r < 4; ++r)
        Ct[wm * 32 + mi * 16 + kg * 4 + r][cl] = acc[mi][ni][r] + bv;
    }
  }
  __syncthreads();
  // 256 thr: cc=(tid&31)*4 floats (16B), rr=tid>>5 (0..7); per instruction a
  // wave covers 2 rows x 512B contiguous -> every 64B sector fully written.
  // tg==127 (rb odd, r==63) redirects to out[b][0][.] with zeros.
  const int b = rb >> 1, tb = (rb & 1) * 64;
  const int rr = tid >> 5, cc = (tid & 31) * 4;
  const f32x4 zv = {0.f, 0.f, 0.f, 0.f};
#pragma unroll
  for (int p = 0; p < 8; ++p) {
    int r = p * 8 + rr;                           // 0..63 within tile
    int tg = tb + r;
    int orow = (tg == 127) ? (b * 128) : (b * 128 + tg + 1);
    float* dst = out + (size_t)orow * 32000 + nb * 128 + cc;
    f32x4 v = (tg == 127) ? zv : *(const f32x4*)&Ct[r][cc];
    __builtin_nontemporal_store(v, (f32x4*)dst);
  }
}

// ---------------------------------------------------------------------------
extern "C" void kernel_launch(void* const* d_in, const int* in_sizes, int n_in,
                              void* d_out, int out_size, void* d_ws, size_t ws_size,
                              hipStream_t stream) {
  const int* src = (const int*)d_in[0];
  const int* tgt = (const int*)d_in[1];
  const float* enc_emb = (const float*)d_in[2];
  const float* enc_Wih = (const float*)d_in[3];
  const float* enc_Whh = (const float*)d_in[4];
  const float* enc_b = (const float*)d_in[5];
  const float* dec_emb = (const float*)d_in[6];
  const float* dec_Wih = (const float*)d_in[7];
  const float* dec_Whh = (const float*)d_in[8];
  const float* dec_b = (const float*)d_in[9];
  const float* fc_W = (const float*)d_in[10];
  const float* fc_b = (const float*)d_in[11];
  float* out = (float*)d_out;
  char* ws = (char*)d_ws;

  float* xg_e = (float*)(ws + WS_XG_E);
  float* xg_d = (float*)(ws + WS_XG_D);
  unsigned short* fcw = (unsigned short*)(ws + WS_FCW);
  unsigned short* hs = (unsigned short*)(ws + WS_HS);
  unsigned short* wte = (unsigned short*)(ws + WS_WTE);
  unsigned short* wtd = (unsigned short*)(ws + WS_WTD);

  cvt_bf16<<<8000, 256, 0, stream>>>(fc_W, fcw, 2048000);
  prep_whalf<<<dim3(1024, 2), 256, 0, stream>>>(enc_Whh, dec_Whh, wte, wtd);
  xg_gemm<<<dim3(8, 32), 256, 0, stream>>>(src, enc_emb, enc_Wih, enc_b, xg_e, 4096);
  xg_gemm<<<dim3(8, 32), 256, 0, stream>>>(tgt, dec_emb, dec_Wih, dec_b, xg_d, 4064);
  lstm_batch<<<32, 512, 0, stream>>>(wte, wtd, xg_e, xg_d, hs);
  fc_gemm<<<dim3(64, 250), 256, 0, stream>>>(hs, fcw, fc_b, out);
}